// Round 7
// baseline (626.785 us; speedup 1.0000x reference)
//
#include <hip/hip_runtime.h>
#include <hip/hip_bf16.h>

#define WS_B 32

typedef __attribute__((ext_vector_type(8))) __bf16 bf16x8;
typedef __attribute__((ext_vector_type(4))) float f32x4;
typedef unsigned short ushort_t;

#define MB(x) ((size_t)(x) << 20)

// ---------------------------------------------------------------- helpers
__device__ __forceinline__ unsigned packpair(float lo, float hi) {
    return ((__float_as_uint(lo) + 0x8000u) >> 16) |
           ((__float_as_uint(hi) + 0x8000u) & 0xffff0000u);
}
__device__ __forceinline__ ushort_t f2bf(float x) {
    return (ushort_t)((__float_as_uint(x) + 0x8000u) >> 16);
}
__device__ __forceinline__ float bf2f(ushort_t u) {
    return __uint_as_float(((unsigned)u) << 16);
}
__device__ __forceinline__ unsigned fuse_word(unsigned f, unsigned s) {
    float lo = __uint_as_float(f << 16) + __uint_as_float(s << 16);
    float hi = __uint_as_float(f & 0xffff0000u) + __uint_as_float(s & 0xffff0000u);
    lo = fmaxf(lo, 0.f);
    hi = fmaxf(hi, 0.f);
    return packpair(lo, hi);
}

// ---------------------------------------------------------------- mega convert
struct CvtArgs {
    const float* src[13];
    ushort_t* dst[13];
    int n4[13];
};
__global__ __launch_bounds__(256) void megacvt_kernel(CvtArgs a) {
    const int t = blockIdx.y;
    const int n = a.n4[t];
    const float4* S = (const float4*)a.src[t];
    uint2* D = (uint2*)a.dst[t];
    for (int i = blockIdx.x * 256 + threadIdx.x; i < n; i += gridDim.x * 256) {
        float4 v = S[i];
        uint2 o;
        o.x = packpair(v.x, v.y);
        o.y = packpair(v.z, v.w);
        D[i] = o;
    }
}

// ---------------------------------------------------------------- batched MFMA GEMM
// Tile 128(M) x 128(N), 256 threads (4 waves, 2x2 wave grid, 64x64/wave).
// Register staging (linear tid*16B LDS layout, stride 32) + next-step prefetch.
struct GemmDesc {
    const ushort_t* A;
    const ushort_t* W;
    const float* bias;
    const float* resid;
    float* C;
    ushort_t* Cb;
    int lda, ldw, ldc, K, relu, nbx, blkStart;
};
struct GemmBatch {
    GemmDesc d[4];
    int nd;
};

__global__ __launch_bounds__(256, 3) void mfma_gemm2(GemmBatch bt) {
    __shared__ ushort_t As[128 * 32];   // 8 KB
    __shared__ ushort_t Bs[128 * 32];   // 8 KB
    int di = 0;
#pragma unroll
    for (int i = 1; i < 4; ++i)
        if (i < bt.nd && (int)blockIdx.x >= bt.d[i].blkStart) di = i;
    const GemmDesc g = bt.d[di];
    const int local = blockIdx.x - g.blkStart;
    const int mb = local / g.nbx;
    const int nb = local - mb * g.nbx;

    const int tid = threadIdx.x;
    const int w = tid >> 6, lane = tid & 63;
    const int wm = w & 1, wn = w >> 1;
    const int l15 = lane & 15, quad = lane >> 4;

    const int arow = tid >> 1;          // 0..127
    const int a16 = (tid & 1) * 16;     // 0 or 16
    const ushort_t* Ap = g.A + (long)(mb * 128 + arow) * g.lda + a16;
    const ushort_t* Bp = g.W + (long)(nb * 128 + arow) * g.ldw + a16;
    ushort_t* Asw = &As[arow * 32 + a16];
    ushort_t* Bsw = &Bs[arow * 32 + a16];

    f32x4 acc[4][4];
#pragma unroll
    for (int i = 0; i < 4; ++i)
#pragma unroll
        for (int j = 0; j < 4; ++j) acc[i][j] = (f32x4)0.f;

    uint4 a0 = *(const uint4*)Ap;
    uint4 a1 = *(const uint4*)(Ap + 8);
    uint4 b0 = *(const uint4*)Bp;
    uint4 b1 = *(const uint4*)(Bp + 8);

    for (int k0 = 0; k0 < g.K; k0 += 32) {
        __syncthreads();
        *(uint4*)Asw = a0; *(uint4*)(Asw + 8) = a1;
        *(uint4*)Bsw = b0; *(uint4*)(Bsw + 8) = b1;
        if (k0 + 32 < g.K) {
            a0 = *(const uint4*)(Ap + k0 + 32);
            a1 = *(const uint4*)(Ap + k0 + 40);
            b0 = *(const uint4*)(Bp + k0 + 32);
            b1 = *(const uint4*)(Bp + k0 + 40);
        }
        __syncthreads();
        bf16x8 af[4], bf[4];
#pragma unroll
        for (int mt = 0; mt < 4; ++mt)
            af[mt] = *(const bf16x8*)&As[(wm * 64 + mt * 16 + l15) * 32 + quad * 8];
#pragma unroll
        for (int nt = 0; nt < 4; ++nt)
            bf[nt] = *(const bf16x8*)&Bs[(wn * 64 + nt * 16 + l15) * 32 + quad * 8];
#pragma unroll
        for (int mt = 0; mt < 4; ++mt)
#pragma unroll
            for (int nt = 0; nt < 4; ++nt)
                acc[mt][nt] = __builtin_amdgcn_mfma_f32_16x16x32_bf16(
                    af[mt], bf[nt], acc[mt][nt], 0, 0, 0);
    }

#pragma unroll
    for (int nt = 0; nt < 4; ++nt) {
        const int col = nb * 128 + wn * 64 + nt * 16 + l15;
        const float bv = g.bias ? g.bias[col] : 0.f;
#pragma unroll
        for (int mt = 0; mt < 4; ++mt) {
            const int row0 = mb * 128 + wm * 64 + mt * 16 + quad * 4;
#pragma unroll
            for (int rg = 0; rg < 4; ++rg) {
                float v = acc[mt][nt][rg] + bv;
                if (g.relu) v = fmaxf(v, 0.f);
                const long off = (long)(row0 + rg) * g.ldc + col;
                if (g.resid) v += g.resid[off];
                if (g.C) g.C[off] = v;
                if (g.Cb) g.Cb[off] = f2bf(v);
            }
        }
    }
}

// ---------------------------------------------------------------- fused h2+score+softmax+rel
// Tile 128(M) x 512(N=full), 512 thr (8 waves, 2m x 4n, each wave 64m x 128n).
// m = r*64 + s, so a 128-row tile = 2 complete r rows -> softmax over s and
// the weighted sem-sum are done in-block. One kernel for the whole rel path.
__global__ __launch_bounds__(512) void h2rel_kernel(
    const ushort_t* __restrict__ Fb,   // (2048,512)  rows r = t*32+b
    const ushort_t* __restrict__ Sb,   // (2048,512)  rows b*64+s
    const ushort_t* __restrict__ w1b,  // (512,512)
    const float* __restrict__ b1,
    const float* __restrict__ w2,
    const ushort_t* __restrict__ semb, // (32,64,512) bf16
    ushort_t* __restrict__ relb)       // (2048,512) bf16
{
    __shared__ ushort_t As[128 * 32];  // 8 KB; reused by reductions after k-loop
    __shared__ ushort_t Bs[512 * 32];  // 32 KB
    const int tid = threadIdx.x;
    const int mb = blockIdx.x;         // 1024 blocks
    const int w = tid >> 6, lane = tid & 63;
    const int wm = w & 1, wn = w >> 1;               // 2 x 4 wave grid
    const int l15 = lane & 15, quad = lane >> 4;

    const int arow = tid >> 2, akc = tid & 3;
    const int m_g = mb * 128 + arow;
    const int r = m_g >> 6, s = m_g & 63, bidx = r & 31;
    const ushort_t* Fp = Fb + (long)r * 512 + akc * 8;
    const ushort_t* Sp = Sb + (long)(bidx * 64 + s) * 512 + akc * 8;
    const ushort_t* Bp = w1b + (long)arow * 512 + akc * 8;   // + j*128 rows
    ushort_t* Asw = &As[arow * 32 + akc * 8];
    ushort_t* Bsw = &Bs[arow * 32 + akc * 8];

    f32x4 acc[4][8];
#pragma unroll
    for (int i = 0; i < 4; ++i)
#pragma unroll
        for (int j = 0; j < 8; ++j) acc[i][j] = (f32x4)0.f;

    uint4 fa = *(const uint4*)Fp;
    uint4 sa = *(const uint4*)Sp;
    uint4 bb[4];
#pragma unroll
    for (int j = 0; j < 4; ++j)
        bb[j] = *(const uint4*)(Bp + (long)j * 128 * 512);

    for (int k0 = 0; k0 < 512; k0 += 32) {
        __syncthreads();
        uint4 o;
        o.x = fuse_word(fa.x, sa.x);
        o.y = fuse_word(fa.y, sa.y);
        o.z = fuse_word(fa.z, sa.z);
        o.w = fuse_word(fa.w, sa.w);
        *(uint4*)Asw = o;
#pragma unroll
        for (int j = 0; j < 4; ++j)
            *(uint4*)(Bsw + j * 128 * 32) = bb[j];
        if (k0 + 32 < 512) {
            fa = *(const uint4*)(Fp + k0 + 32);
            sa = *(const uint4*)(Sp + k0 + 32);
#pragma unroll
            for (int j = 0; j < 4; ++j)
                bb[j] = *(const uint4*)(Bp + (long)j * 128 * 512 + k0 + 32);
        }
        __syncthreads();
        bf16x8 af[4], bf[8];
#pragma unroll
        for (int mt = 0; mt < 4; ++mt)
            af[mt] = *(const bf16x8*)&As[(wm * 64 + mt * 16 + l15) * 32 + quad * 8];
#pragma unroll
        for (int nt = 0; nt < 8; ++nt) {
            const int brow = (nt >> 2) * 256 + wn * 64 + (nt & 3) * 16 + l15;
            bf[nt] = *(const bf16x8*)&Bs[brow * 32 + quad * 8];
        }
#pragma unroll
        for (int mt = 0; mt < 4; ++mt)
#pragma unroll
            for (int nt = 0; nt < 8; ++nt)
                acc[mt][nt] = __builtin_amdgcn_mfma_f32_16x16x32_bf16(
                    af[mt], bf[nt], acc[mt][nt], 0, 0, 0);
    }
    __syncthreads();   // As now dead; reuse for reductions

    // ---- per-row score partials: sum_cols relu(acc + b1[col]) * w2[col]
    float sp[4][4];
#pragma unroll
    for (int mt = 0; mt < 4; ++mt)
#pragma unroll
        for (int rg = 0; rg < 4; ++rg) sp[mt][rg] = 0.f;
#pragma unroll
    for (int nt = 0; nt < 8; ++nt) {
        const int col = (nt >> 2) * 256 + wn * 64 + (nt & 3) * 16 + l15;
        const float cb = b1[col];
        const float cw = w2[col];
#pragma unroll
        for (int mt = 0; mt < 4; ++mt) {
#pragma unroll
            for (int rg = 0; rg < 4; ++rg)
                sp[mt][rg] += fmaxf(acc[mt][nt][rg] + cb, 0.f) * cw;
        }
    }
    float* scred = (float*)As;                 // [128][4]
#pragma unroll
    for (int mt = 0; mt < 4; ++mt)
#pragma unroll
        for (int rg = 0; rg < 4; ++rg) {
            float v = sp[mt][rg];
            v += __shfl_xor(v, 1);
            v += __shfl_xor(v, 2);
            v += __shfl_xor(v, 4);
            v += __shfl_xor(v, 8);
            if (l15 == 0)
                scred[(wm * 64 + mt * 16 + quad * 4 + rg) * 4 + wn] = v;
        }
    __syncthreads();

    float* sm = ((float*)As) + 512;            // [128] complete scores
    if (tid < 128)
        sm[tid] = scred[tid * 4] + scred[tid * 4 + 1]
                + scred[tid * 4 + 2] + scred[tid * 4 + 3];
    __syncthreads();

    // ---- softmax over s (64) per r-half: waves 0 and 1, one r each
    float* aw = ((float*)As) + 640;            // [128] softmax weights
    if (tid < 128) {
        float t = sm[tid];
        float mx = t;
#pragma unroll
        for (int off = 32; off > 0; off >>= 1) mx = fmaxf(mx, __shfl_xor(mx, off));
        float e = __expf(t - mx);
        float su = e;
#pragma unroll
        for (int off = 32; off > 0; off >>= 1) su += __shfl_xor(su, off);
        aw[tid] = e / su;
    }
    __syncthreads();

    // ---- rel[r,:] = sum_s a[s] * sem[b,s,:]   (2 r rows, 512 d each)
    {
        const int rhalf = tid >> 8;            // 0..1
        const int d2 = (tid & 255) * 2;        // 0,2,..,510
        const int rr = mb * 2 + rhalf;
        const int bb2 = rr & 31;
        const float* a = aw + rhalf * 64;
        const ushort_t* sp2 = semb + (long)bb2 * 64 * 512 + d2;
        float a0 = 0.f, a1 = 0.f;
        for (int s2 = 0; s2 < 64; ++s2) {
            const unsigned u = *(const unsigned*)(sp2 + s2 * 512);
            const float wgt = a[s2];
            a0 += wgt * __uint_as_float(u << 16);
            a1 += wgt * __uint_as_float(u & 0xffff0000u);
        }
        *(unsigned*)(relb + (long)rr * 512 + d2) = packpair(a0, a1);
    }
}

// ---------------------------------------------------------------- attention v2
__global__ __launch_bounds__(256) void attn2_kernel(
    const ushort_t* __restrict__ Qm, int ldq, int qoff,
    const ushort_t* __restrict__ Km, int ldk, int koff,
    const ushort_t* __restrict__ Vm, int ldv, int voff,
    ushort_t* __restrict__ O,          // (2048,512) bf16
    int Lk)
{
    __shared__ float sQT[64 * 34];
    __shared__ float sKT[64 * 68];
    __shared__ float sS[32 * 260];
    __shared__ float sredm[8 * 34];
    __shared__ float sreds[8 * 34];
    const int tid = threadIdx.x;
    const int b  = blockIdx.x >> 4;
    const int h  = (blockIdx.x >> 1) & 7;
    const int qt = blockIdx.x & 1;
    const int L8 = Lk >> 3;

    {
        const int q = tid >> 3, c = tid & 7;
        const int qg = qt * 32 + q;
        const ushort_t* pp = Qm + (long)(qg * WS_B + b) * ldq + qoff + h * 64 + c * 8;
        uint4 u = *(const uint4*)pp;
        const ushort_t* us = (const ushort_t*)&u;
#pragma unroll
        for (int i = 0; i < 8; ++i)
            sQT[(c * 8 + i) * 34 + q] = bf2f(us[i]);
    }

    const int k4 = (tid & 15) * 4;
    const int q2 = (tid >> 4) * 2;

    for (int kt = 0; kt < Lk; kt += 64) {
        __syncthreads();
        {
            const int kk = tid >> 3, c = tid & 7;
#pragma unroll
            for (int half = 0; half < 2; ++half) {
                const int kr = kk + half * 32;
                const ushort_t* pp = Km + (long)((kt + kr) * WS_B + b) * ldk + koff + h * 64 + c * 8;
                uint4 u = *(const uint4*)pp;
                const ushort_t* us = (const ushort_t*)&u;
#pragma unroll
                for (int i = 0; i < 8; ++i)
                    sKT[(c * 8 + i) * 68 + kr] = bf2f(us[i]);
            }
        }
        __syncthreads();
        float acc[2][4] = {{0.f, 0.f, 0.f, 0.f}, {0.f, 0.f, 0.f, 0.f}};
        for (int d = 0; d < 64; ++d) {
            const float qa = sQT[d * 34 + q2];
            const float qb = sQT[d * 34 + q2 + 1];
            const float4 kv = *(const float4*)&sKT[d * 68 + k4];
            acc[0][0] += qa * kv.x; acc[0][1] += qa * kv.y;
            acc[0][2] += qa * kv.z; acc[0][3] += qa * kv.w;
            acc[1][0] += qb * kv.x; acc[1][1] += qb * kv.y;
            acc[1][2] += qb * kv.z; acc[1][3] += qb * kv.w;
        }
#pragma unroll
        for (int i = 0; i < 2; ++i) {
            float4 v;
            v.x = acc[i][0] * 0.125f; v.y = acc[i][1] * 0.125f;
            v.z = acc[i][2] * 0.125f; v.w = acc[i][3] * 0.125f;
            *(float4*)&sS[(q2 + i) * 260 + kt + k4] = v;
        }
    }
    __syncthreads();

    {
        const int q = tid & 31, part = tid >> 5;
        const int kb = part * L8;
        float m = -1e30f;
        for (int k = 0; k < L8; ++k) m = fmaxf(m, sS[q * 260 + kb + k]);
        sredm[part * 34 + q] = m;
        __syncthreads();
        float M = sredm[q];
#pragma unroll
        for (int pz = 1; pz < 8; ++pz) M = fmaxf(M, sredm[pz * 34 + q]);
        float su = 0.f;
        for (int k = 0; k < L8; ++k) {
            float e = __expf(sS[q * 260 + kb + k] - M);
            sS[q * 260 + kb + k] = e;
            su += e;
        }
        sreds[part * 34 + q] = su;
    }
    __syncthreads();

    const int d4 = (tid & 15) * 4;
    float o[2][4] = {{0.f, 0.f, 0.f, 0.f}, {0.f, 0.f, 0.f, 0.f}};
    float* sV = sKT;
    for (int kt = 0; kt < Lk; kt += 64) {
        __syncthreads();
        {
            const int kk = tid >> 3, c = tid & 7;
#pragma unroll
            for (int half = 0; half < 2; ++half) {
                const int kr = kk + half * 32;
                const ushort_t* pp = Vm + (long)((kt + kr) * WS_B + b) * ldv + voff + h * 64 + c * 8;
                uint4 u = *(const uint4*)pp;
                const ushort_t* us = (const ushort_t*)&u;
                float4 w0, w1;
                w0.x = bf2f(us[0]); w0.y = bf2f(us[1]);
                w0.z = bf2f(us[2]); w0.w = bf2f(us[3]);
                w1.x = bf2f(us[4]); w1.y = bf2f(us[5]);
                w1.z = bf2f(us[6]); w1.w = bf2f(us[7]);
                *(float4*)&sV[kr * 68 + c * 8] = w0;
                *(float4*)&sV[kr * 68 + c * 8 + 4] = w1;
            }
        }
        __syncthreads();
        for (int k = 0; k < 64; ++k) {
            const float p0 = sS[q2 * 260 + kt + k];
            const float p1 = sS[(q2 + 1) * 260 + kt + k];
            const float4 vv = *(const float4*)&sV[k * 68 + d4];
            o[0][0] += p0 * vv.x; o[0][1] += p0 * vv.y;
            o[0][2] += p0 * vv.z; o[0][3] += p0 * vv.w;
            o[1][0] += p1 * vv.x; o[1][1] += p1 * vv.y;
            o[1][2] += p1 * vv.z; o[1][3] += p1 * vv.w;
        }
    }

#pragma unroll
    for (int i = 0; i < 2; ++i) {
        float su = 0.f;
#pragma unroll
        for (int pz = 0; pz < 8; ++pz) su += sreds[pz * 34 + q2 + i];
        const float inv = 1.f / su;
        const int qg = qt * 32 + q2 + i;
        ushort_t* op = O + (long)(qg * WS_B + b) * 512 + h * 64 + d4;
        uint2 pk;
        pk.x = packpair(o[i][0] * inv, o[i][1] * inv);
        pk.y = packpair(o[i][2] * inv, o[i][3] * inv);
        *(uint2*)op = pk;
    }
}

// ---------------------------------------------------------------- layernorm (dual out)
__global__ __launch_bounds__(256) void ln_kernel(
    const float* __restrict__ X,
    const float* __restrict__ g,
    const float* __restrict__ be,
    float* __restrict__ Y,
    ushort_t* __restrict__ Yb)
{
    const int row = blockIdx.x * 4 + (threadIdx.x >> 6);
    const int lane = threadIdx.x & 63;
    const float4* xp = (const float4*)(X + (long)row * 512);
    float4 x0 = xp[lane], x1 = xp[lane + 64];
    float sum = x0.x + x0.y + x0.z + x0.w + x1.x + x1.y + x1.z + x1.w;
    float sq = x0.x * x0.x + x0.y * x0.y + x0.z * x0.z + x0.w * x0.w
             + x1.x * x1.x + x1.y * x1.y + x1.z * x1.z + x1.w * x1.w;
#pragma unroll
    for (int off = 32; off > 0; off >>= 1) {
        sum += __shfl_xor(sum, off);
        sq += __shfl_xor(sq, off);
    }
    const float mu = sum * (1.f / 512.f);
    const float var = sq * (1.f / 512.f) - mu * mu;
    const float rs = rsqrtf(var + 1e-5f);
    const float4* gp = (const float4*)g;
    const float4* bp = (const float4*)be;
    float4 g0 = gp[lane], g1 = gp[lane + 64], b0 = bp[lane], b1 = bp[lane + 64];
    float4 y0, y1;
    y0.x = (x0.x - mu) * rs * g0.x + b0.x;
    y0.y = (x0.y - mu) * rs * g0.y + b0.y;
    y0.z = (x0.z - mu) * rs * g0.z + b0.z;
    y0.w = (x0.w - mu) * rs * g0.w + b0.w;
    y1.x = (x1.x - mu) * rs * g1.x + b1.x;
    y1.y = (x1.y - mu) * rs * g1.y + b1.y;
    y1.z = (x1.z - mu) * rs * g1.z + b1.z;
    y1.w = (x1.w - mu) * rs * g1.w + b1.w;
    float4* yp = (float4*)(Y + (long)row * 512);
    yp[lane] = y0; yp[lane + 64] = y1;
    if (Yb) {
        uint2* ybp = (uint2*)(Yb + (long)row * 512);
        uint2 p0, p1;
        p0.x = packpair(y0.x, y0.y); p0.y = packpair(y0.z, y0.w);
        p1.x = packpair(y1.x, y1.y); p1.y = packpair(y1.z, y1.w);
        ybp[lane] = p0; ybp[lane + 64] = p1;
    }
}

// ---------------------------------------------------------------- launch helpers
static inline GemmDesc mkdesc(const ushort_t* A, int lda, const ushort_t* W, int ldw,
                              const float* bias, const float* resid, float* C,
                              ushort_t* Cb, int ldc, int N, int K, int relu,
                              int blkStart)
{
    GemmDesc d;
    d.A = A; d.W = W; d.bias = bias; d.resid = resid; d.C = C; d.Cb = Cb;
    d.lda = lda; d.ldw = ldw; d.ldc = ldc; d.K = K; d.relu = relu;
    d.nbx = N / 128;
    d.blkStart = blkStart;
    return d;
}
static inline void mgemm(hipStream_t s, const ushort_t* A, int lda,
                         const ushort_t* W, int ldw, const float* bias,
                         const float* resid, float* C, ushort_t* Cb,
                         int ldc, int M, int N, int K, bool relu)
{
    GemmBatch bt;
    bt.nd = 1;
    bt.d[0] = mkdesc(A, lda, W, ldw, bias, resid, C, Cb, ldc, N, K, relu ? 1 : 0, 0);
    bt.d[1] = bt.d[0]; bt.d[2] = bt.d[0]; bt.d[3] = bt.d[0];
    mfma_gemm2<<<(M / 128) * (N / 128), 256, 0, s>>>(bt);
}

extern "C" void kernel_launch(void* const* d_in, const int* in_sizes, int n_in,
                              void* d_out, int out_size, void* d_ws, size_t ws_size,
                              hipStream_t stream)
{
    (void)in_sizes; (void)n_in; (void)out_size; (void)ws_size;
    const float* tgt       = (const float*)d_in[0];
    const float* memory    = (const float*)d_in[1];
    const float* semantics = (const float*)d_in[2];
    const float* pt_wqkv   = (const float*)d_in[3];
    const float* pt_bqkv   = (const float*)d_in[4];
    const float* pt_wo     = (const float*)d_in[5];
    const float* pt_bo     = (const float*)d_in[6];
    const float* sa_wqkv   = (const float*)d_in[7];
    const float* sa_bqkv   = (const float*)d_in[8];
    const float* sa_wo     = (const float*)d_in[9];
    const float* sa_bo     = (const float*)d_in[10];
    const float* ca_wqkv   = (const float*)d_in[11];
    const float* ca_bqkv   = (const float*)d_in[12];
    const float* ca_wo     = (const float*)d_in[13];
    const float* ca_bo     = (const float*)d_in[14];
    const float* mlp_w0    = (const float*)d_in[15];
    const float* mlp_b0    = (const float*)d_in[16];
    const float* mlp_w1    = (const float*)d_in[17];
    const float* mlp_b1    = (const float*)d_in[18];
    const float* mlp_w2    = (const float*)d_in[19];
    const float* ffn_w1    = (const float*)d_in[21];
    const float* ffn_b1    = (const float*)d_in[22];
    const float* ffn_w2    = (const float*)d_in[23];
    const float* ffn_b2    = (const float*)d_in[24];
    const float* ln1_g     = (const float*)d_in[25];
    const float* ln1_b     = (const float*)d_in[26];
    const float* ln2_g     = (const float*)d_in[27];
    const float* ln2_b     = (const float*)d_in[28];
    const float* ln3_g     = (const float*)d_in[29];
    const float* ln3_b     = (const float*)d_in[30];

    char* p = (char*)d_ws;
    // weights (persist): [0, 11.5 MB)
    ushort_t* w0b   = (ushort_t*)(p + 0);          // 512x1024   1.0 MB
    ushort_t* w1b   = (ushort_t*)(p + MB(1));      // 512x512    0.5
    ushort_t* ptwb  = (ushort_t*)(p + 1572864);    // 1536x512   1.5
    ushort_t* ptob  = (ushort_t*)(p + MB(3));      // 512x512    0.5
    ushort_t* sawb  = (ushort_t*)(p + 3670016);    // 1536x512   1.5
    ushort_t* saob  = (ushort_t*)(p + MB(5));      // 512x512    0.5
    ushort_t* cawb  = (ushort_t*)(p + 5767168);    // 1536x512   1.5
    ushort_t* caob  = (ushort_t*)(p + MB(7));      // 512x512    0.5
    ushort_t* f1b   = (ushort_t*)(p + 7864320);    // 2048x512   2.0
    ushort_t* f2b   = (ushort_t*)(p + 9961472);    // 512x2048   2.0
    // activations:
    ushort_t* memb  = (ushort_t*)(p + MB(12));     // 8192x512   8   (dies @cakv)
    ushort_t* cakvb = (ushort_t*)(p + MB(20));     // 8192x1024 16   (-> attn ca)
    ushort_t* tgtb  = (ushort_t*)(p + MB(36));     // 2048x512   2
    ushort_t* semb  = (ushort_t*)(p + MB(38));     // 2048x512   2
    ushort_t* Fb    = (ushort_t*)(p + MB(40));     // 2
    ushort_t* Sb    = (ushort_t*)(p + MB(42));     // 2
    ushort_t* relb  = (ushort_t*)(p + MB(45));     // 2
    ushort_t* Ob    = (ushort_t*)(p + MB(47));     // 2
    float*    x1f   = (float*)(p + MB(49));        // 4
    ushort_t* ptqb  = (ushort_t*)(p + MB(53));     // 2  [53,55) — NOT over memb
    // aliases over dead regions:
    ushort_t* ptkvb = (ushort_t*)(p + MB(14));     // 4  over memb (dead after cakv)
    ushort_t* x1b   = (ushort_t*)(p + MB(18));     // 2  over memb
    ushort_t* saqkvb= (ushort_t*)(p + MB(38));     // 6  over semb/Fb/Sb (dead)
    float*    yf    = (float*)(p + MB(12));        // 4  over memb head (dead)
    float*    x2f   = (float*)(p + MB(16));        // 4  over ptkvb (dead by then)
    ushort_t* x2b   = (ushort_t*)(p + MB(36));     // 2  over tgtb (dead)
    ushort_t* caqb  = (ushort_t*)(p + MB(44));     // 2  over relb-area (dead)
    float*    x3f   = (float*)(p + MB(40));        // 4  over saqkvb (dead)
    ushort_t* x3b   = (ushort_t*)(p + MB(38));     // 2  over saqkvb (dead)
    ushort_t* hb    = (ushort_t*)(p + MB(20));     // 8  over cakvb (dead)

    // ---- 1. convert everything to bf16 (one launch)
    CvtArgs ca;
    ca.src[0]  = tgt;       ca.dst[0]  = tgtb;  ca.n4[0]  = 262144;
    ca.src[1]  = semantics; ca.dst[1]  = semb;  ca.n4[1]  = 262144;
    ca.src[2]  = memory;    ca.dst[2]  = memb;  ca.n4[2]  = 1048576;
    ca.src[3]  = mlp_w0;    ca.dst[3]  = w0b;   ca.n4[3]  = 131072;
    ca.src[4]  = mlp_w1;    ca.dst[4]  = w1b;   ca.n4[4]  = 65536;
    ca.src[5]  = pt_wqkv;   ca.dst[5]  = ptwb;  ca.n4[5]  = 196608;
    ca.src[6]  = pt_wo;     ca.dst[6]  = ptob;  ca.n4[6]  = 65536;
    ca.src[7]  = sa_wqkv;   ca.dst[7]  = sawb;  ca.n4[7]  = 196608;
    ca.src[8]  = sa_wo;     ca.dst[8]  = saob;  ca.n4[8]  = 65536;
    ca.src[9]  = ca_wqkv;   ca.dst[9]  = cawb;  ca.n4[9]  = 196608;
    ca.src[10] = ca_wo;     ca.dst[10] = caob;  ca.n4[10] = 65536;
    ca.src[11] = ffn_w1;    ca.dst[11] = f1b;   ca.n4[11] = 262144;
    ca.src[12] = ffn_w2;    ca.dst[12] = f2b;   ca.n4[12] = 262144;
    megacvt_kernel<<<dim3(1024, 13), 256, 0, stream>>>(ca);

    // ---- 2. batched independent GEMMs: cakv(512) + F(64) + Smat(64) + ptq(64)
    {
        GemmBatch bt;
        bt.nd = 4;
        bt.d[0] = mkdesc(memb, 512, cawb + 512 * 512, 512, ca_bqkv + 512, nullptr,
                         nullptr, cakvb, 1024, 1024, 512, 0, 0);
        bt.d[1] = mkdesc(tgtb, 512, w0b, 1024, mlp_b0, nullptr,
                         nullptr, Fb, 512, 512, 512, 0, 512);
        bt.d[2] = mkdesc(semb, 512, w0b + 512, 1024, nullptr, nullptr,
                         nullptr, Sb, 512, 512, 512, 0, 576);
        bt.d[3] = mkdesc(tgtb, 512, ptwb, 512, pt_bqkv, nullptr,
                         nullptr, ptqb, 512, 512, 512, 0, 640);
        mfma_gemm2<<<704, 256, 0, stream>>>(bt);
    }

    // ---- rel path: single fused kernel (h2 GEMM + score + softmax + sem-sum)
    h2rel_kernel<<<1024, 512, 0, stream>>>(Fb, Sb, w1b, mlp_b1, mlp_w2, semb, relb);

    // ---- pt attention
    mgemm(stream, relb, 512, ptwb + 512 * 512, 512, pt_bqkv + 512, nullptr,
          nullptr, ptkvb, 1024, 2048, 1024, 512, false);
    attn2_kernel<<<512, 256, 0, stream>>>(ptqb, 512, 0, ptkvb, 1024, 0,
                                          ptkvb, 1024, 512, Ob, 64);
    mgemm(stream, Ob, 512, ptob, 512, pt_bo, tgt, x1f, x1b, 512,
          2048, 512, 512, false);

    // ---- self attention + ln1
    mgemm(stream, x1b, 512, sawb, 512, sa_bqkv, nullptr, nullptr, saqkvb, 1536,
          2048, 1536, 512, false);
    attn2_kernel<<<512, 256, 0, stream>>>(saqkvb, 1536, 0, saqkvb, 1536, 512,
                                          saqkvb, 1536, 1024, Ob, 64);
    mgemm(stream, Ob, 512, saob, 512, sa_bo, x1f, yf, nullptr, 512,
          2048, 512, 512, false);
    ln_kernel<<<512, 256, 0, stream>>>(yf, ln1_g, ln1_b, x2f, x2b);

    // ---- cross attention + ln2
    mgemm(stream, x2b, 512, cawb, 512, ca_bqkv, nullptr, nullptr, caqb, 512,
          2048, 512, 512, false);
    attn2_kernel<<<512, 256, 0, stream>>>(caqb, 512, 0, cakvb, 1024, 0,
                                          cakvb, 1024, 512, Ob, 256);
    mgemm(stream, Ob, 512, caob, 512, ca_bo, x2f, yf, nullptr, 512,
          2048, 512, 512, false);
    ln_kernel<<<512, 256, 0, stream>>>(yf, ln2_g, ln2_b, x3f, x3b);

    // ---- FFN + ln3 -> out
    mgemm(stream, x3b, 512, f1b, 512, ffn_b1, nullptr, nullptr, hb, 2048,
          2048, 2048, 512, true);
    mgemm(stream, hb, 2048, f2b, 2048, ffn_b2, x3f, yf, nullptr, 512,
          2048, 512, 2048, false);
    ln_kernel<<<512, 256, 0, stream>>>(yf, ln3_g, ln3_b, (float*)d_out, nullptr);
}

// Round 8
// 520.573 us; speedup vs baseline: 1.2040x; 1.2040x over previous
//
#include <hip/hip_runtime.h>
#include <hip/hip_bf16.h>

#define WS_B 32

typedef __attribute__((ext_vector_type(8))) __bf16 bf16x8;
typedef __attribute__((ext_vector_type(4))) float f32x4;
typedef unsigned short ushort_t;

#define MB(x) ((size_t)(x) << 20)

// ---------------------------------------------------------------- helpers
__device__ __forceinline__ unsigned packpair(float lo, float hi) {
    return ((__float_as_uint(lo) + 0x8000u) >> 16) |
           ((__float_as_uint(hi) + 0x8000u) & 0xffff0000u);
}
__device__ __forceinline__ ushort_t f2bf(float x) {
    return (ushort_t)((__float_as_uint(x) + 0x8000u) >> 16);
}
__device__ __forceinline__ float bf2f(ushort_t u) {
    return __uint_as_float(((unsigned)u) << 16);
}
__device__ __forceinline__ unsigned fuse_word(unsigned f, unsigned s) {
    float lo = __uint_as_float(f << 16) + __uint_as_float(s << 16);
    float hi = __uint_as_float(f & 0xffff0000u) + __uint_as_float(s & 0xffff0000u);
    lo = fmaxf(lo, 0.f);
    hi = fmaxf(hi, 0.f);
    return packpair(lo, hi);
}

// ---------------------------------------------------------------- mega convert
struct CvtArgs {
    const float* src[13];
    ushort_t* dst[13];
    int n4[13];
};
__global__ __launch_bounds__(256) void megacvt_kernel(CvtArgs a) {
    const int t = blockIdx.y;
    const int n = a.n4[t];
    const float4* S = (const float4*)a.src[t];
    uint2* D = (uint2*)a.dst[t];
    for (int i = blockIdx.x * 256 + threadIdx.x; i < n; i += gridDim.x * 256) {
        float4 v = S[i];
        uint2 o;
        o.x = packpair(v.x, v.y);
        o.y = packpair(v.z, v.w);
        D[i] = o;
    }
}

// ---------------------------------------------------------------- GEMM descriptors
struct GemmDesc {
    const ushort_t* A;
    const ushort_t* W;
    const float* bias;
    const float* resid;
    float* C;
    ushort_t* Cb;
    int lda, ldw, ldc, K, relu, nbx, blkStart;
};
struct GemmBatch {
    GemmDesc d[4];
    int nd;
};

// ---------------------------------------------------------------- MFMA GEMM 128x128
// 256 threads (4 waves, 2x2 wave grid). Register staging + prefetch.
__global__ __launch_bounds__(256, 3) void mfma_gemm2(GemmBatch bt) {
    __shared__ ushort_t As[128 * 32];   // 8 KB
    __shared__ ushort_t Bs[128 * 32];   // 8 KB
    int di = 0;
#pragma unroll
    for (int i = 1; i < 4; ++i)
        if (i < bt.nd && (int)blockIdx.x >= bt.d[i].blkStart) di = i;
    const GemmDesc g = bt.d[di];
    const int local = blockIdx.x - g.blkStart;
    const int mb = local / g.nbx;
    const int nb = local - mb * g.nbx;

    const int tid = threadIdx.x;
    const int w = tid >> 6, lane = tid & 63;
    const int wm = w & 1, wn = w >> 1;
    const int l15 = lane & 15, quad = lane >> 4;

    const int arow = tid >> 1;
    const int a16 = (tid & 1) * 16;
    const ushort_t* Ap = g.A + (long)(mb * 128 + arow) * g.lda + a16;
    const ushort_t* Bp = g.W + (long)(nb * 128 + arow) * g.ldw + a16;
    ushort_t* Asw = &As[arow * 32 + a16];
    ushort_t* Bsw = &Bs[arow * 32 + a16];

    f32x4 acc[4][4];
#pragma unroll
    for (int i = 0; i < 4; ++i)
#pragma unroll
        for (int j = 0; j < 4; ++j) acc[i][j] = (f32x4)0.f;

    uint4 a0 = *(const uint4*)Ap;
    uint4 a1 = *(const uint4*)(Ap + 8);
    uint4 b0 = *(const uint4*)Bp;
    uint4 b1 = *(const uint4*)(Bp + 8);

    for (int k0 = 0; k0 < g.K; k0 += 32) {
        __syncthreads();
        *(uint4*)Asw = a0; *(uint4*)(Asw + 8) = a1;
        *(uint4*)Bsw = b0; *(uint4*)(Bsw + 8) = b1;
        if (k0 + 32 < g.K) {
            a0 = *(const uint4*)(Ap + k0 + 32);
            a1 = *(const uint4*)(Ap + k0 + 40);
            b0 = *(const uint4*)(Bp + k0 + 32);
            b1 = *(const uint4*)(Bp + k0 + 40);
        }
        __syncthreads();
        bf16x8 af[4], bf[4];
#pragma unroll
        for (int mt = 0; mt < 4; ++mt)
            af[mt] = *(const bf16x8*)&As[(wm * 64 + mt * 16 + l15) * 32 + quad * 8];
#pragma unroll
        for (int nt = 0; nt < 4; ++nt)
            bf[nt] = *(const bf16x8*)&Bs[(wn * 64 + nt * 16 + l15) * 32 + quad * 8];
#pragma unroll
        for (int mt = 0; mt < 4; ++mt)
#pragma unroll
            for (int nt = 0; nt < 4; ++nt)
                acc[mt][nt] = __builtin_amdgcn_mfma_f32_16x16x32_bf16(
                    af[mt], bf[nt], acc[mt][nt], 0, 0, 0);
    }

#pragma unroll
    for (int nt = 0; nt < 4; ++nt) {
        const int col = nb * 128 + wn * 64 + nt * 16 + l15;
        const float bv = g.bias ? g.bias[col] : 0.f;
#pragma unroll
        for (int mt = 0; mt < 4; ++mt) {
            const int row0 = mb * 128 + wm * 64 + mt * 16 + quad * 4;
#pragma unroll
            for (int rg = 0; rg < 4; ++rg) {
                float v = acc[mt][nt][rg] + bv;
                if (g.relu) v = fmaxf(v, 0.f);
                const long off = (long)(row0 + rg) * g.ldc + col;
                if (g.resid) v += g.resid[off];
                if (g.C) g.C[off] = v;
                if (g.Cb) g.Cb[off] = f2bf(v);
            }
        }
    }
}

// ---------------------------------------------------------------- MFMA GEMM 64x128
// 128 threads (2 waves over n). Small-M chain GEMMs: 2x block count of gemm2.
__global__ __launch_bounds__(128, 3) void mfma_gemm3(GemmBatch bt) {
    __shared__ ushort_t As[64 * 32];    // 4 KB
    __shared__ ushort_t Bs[128 * 32];   // 8 KB
    int di = 0;
#pragma unroll
    for (int i = 1; i < 4; ++i)
        if (i < bt.nd && (int)blockIdx.x >= bt.d[i].blkStart) di = i;
    const GemmDesc g = bt.d[di];
    const int local = blockIdx.x - g.blkStart;
    const int mb = local / g.nbx;
    const int nb = local - mb * g.nbx;

    const int tid = threadIdx.x;
    const int wn = tid >> 6, lane = tid & 63;
    const int l15 = lane & 15, quad = lane >> 4;

    const int ar = tid >> 1, ac = (tid & 1) * 16;
    const ushort_t* Ap = g.A + (long)(mb * 64 + ar) * g.lda + ac;
    const ushort_t* Bp = g.W + (long)(nb * 128 + tid) * g.ldw;
    ushort_t* Asw = &As[ar * 32 + ac];
    ushort_t* Bsw = &Bs[tid * 32];

    f32x4 acc[4][4];
#pragma unroll
    for (int i = 0; i < 4; ++i)
#pragma unroll
        for (int j = 0; j < 4; ++j) acc[i][j] = (f32x4)0.f;

    uint4 a0 = *(const uint4*)Ap;
    uint4 a1 = *(const uint4*)(Ap + 8);
    uint4 b0 = *(const uint4*)Bp;
    uint4 b1 = *(const uint4*)(Bp + 8);
    uint4 b2 = *(const uint4*)(Bp + 16);
    uint4 b3 = *(const uint4*)(Bp + 24);

    for (int k0 = 0; k0 < g.K; k0 += 32) {
        __syncthreads();
        *(uint4*)Asw = a0; *(uint4*)(Asw + 8) = a1;
        *(uint4*)Bsw = b0; *(uint4*)(Bsw + 8) = b1;
        *(uint4*)(Bsw + 16) = b2; *(uint4*)(Bsw + 24) = b3;
        if (k0 + 32 < g.K) {
            a0 = *(const uint4*)(Ap + k0 + 32);
            a1 = *(const uint4*)(Ap + k0 + 40);
            b0 = *(const uint4*)(Bp + k0 + 32);
            b1 = *(const uint4*)(Bp + k0 + 40);
            b2 = *(const uint4*)(Bp + k0 + 48);
            b3 = *(const uint4*)(Bp + k0 + 56);
        }
        __syncthreads();
        bf16x8 af[4], bf[4];
#pragma unroll
        for (int mt = 0; mt < 4; ++mt)
            af[mt] = *(const bf16x8*)&As[(mt * 16 + l15) * 32 + quad * 8];
#pragma unroll
        for (int nt = 0; nt < 4; ++nt)
            bf[nt] = *(const bf16x8*)&Bs[(wn * 64 + nt * 16 + l15) * 32 + quad * 8];
#pragma unroll
        for (int mt = 0; mt < 4; ++mt)
#pragma unroll
            for (int nt = 0; nt < 4; ++nt)
                acc[mt][nt] = __builtin_amdgcn_mfma_f32_16x16x32_bf16(
                    af[mt], bf[nt], acc[mt][nt], 0, 0, 0);
    }

#pragma unroll
    for (int nt = 0; nt < 4; ++nt) {
        const int col = nb * 128 + wn * 64 + nt * 16 + l15;
        const float bv = g.bias ? g.bias[col] : 0.f;
#pragma unroll
        for (int mt = 0; mt < 4; ++mt) {
            const int row0 = mb * 64 + mt * 16 + quad * 4;
#pragma unroll
            for (int rg = 0; rg < 4; ++rg) {
                float v = acc[mt][nt][rg] + bv;
                if (g.relu) v = fmaxf(v, 0.f);
                const long off = (long)(row0 + rg) * g.ldc + col;
                if (g.resid) v += g.resid[off];
                if (g.C) g.C[off] = v;
                if (g.Cb) g.Cb[off] = f2bf(v);
            }
        }
    }
}

// ---------------------------------------------------------------- h2 scores (MFMA)
// Round-3 structure verbatim (measured 101 us): stride-32 LDS, register staging.
__global__ __launch_bounds__(512, 2) void h2score_kernel(
    const ushort_t* __restrict__ Fb,   // (2048,512)
    const ushort_t* __restrict__ Sb,   // (2048,512) rows b*64+s
    const ushort_t* __restrict__ w1b,  // (512,512)
    const float* __restrict__ b1,
    const float* __restrict__ w2,
    float* __restrict__ scores4)       // (2, 131072)
{
    __shared__ ushort_t As[128 * 32];
    __shared__ ushort_t Bs[256 * 32];
    __shared__ float scred[128 * 4];
    const int tid = threadIdx.x;
    const int mb = blockIdx.x, nb = blockIdx.y;
    const int w = tid >> 6, lane = tid & 63;
    const int wm = w & 1, wn = w >> 1;
    const int l15 = lane & 15, quad = lane >> 4;

    const int arow = tid >> 2, akc = tid & 3;
    const int m_g = mb * 128 + arow;
    const int r = m_g >> 6, s = m_g & 63, bidx = r & 31;
    const ushort_t* Fp = Fb + (long)r * 512 + akc * 8;
    const ushort_t* Sp = Sb + (long)(bidx * 64 + s) * 512 + akc * 8;
    const ushort_t* Bp0 = w1b + (long)(nb * 256 + arow) * 512 + akc * 8;
    const ushort_t* Bp1 = Bp0 + (long)128 * 512;
    ushort_t* Asw = &As[arow * 32 + akc * 8];
    ushort_t* Bsw0 = &Bs[arow * 32 + akc * 8];
    ushort_t* Bsw1 = Bsw0 + 128 * 32;

    f32x4 acc[4][4];
#pragma unroll
    for (int i = 0; i < 4; ++i)
#pragma unroll
        for (int j = 0; j < 4; ++j) acc[i][j] = (f32x4)0.f;

    for (int k0 = 0; k0 < 512; k0 += 32) {
        uint4 fa = *(const uint4*)(Fp + k0);
        uint4 sa = *(const uint4*)(Sp + k0);
        uint4 bb0 = *(const uint4*)(Bp0 + k0);
        uint4 bb1 = *(const uint4*)(Bp1 + k0);
        __syncthreads();
        uint4 o;
        o.x = fuse_word(fa.x, sa.x);
        o.y = fuse_word(fa.y, sa.y);
        o.z = fuse_word(fa.z, sa.z);
        o.w = fuse_word(fa.w, sa.w);
        *(uint4*)Asw = o;
        *(uint4*)Bsw0 = bb0;
        *(uint4*)Bsw1 = bb1;
        __syncthreads();
        bf16x8 af[4], bf[4];
#pragma unroll
        for (int mt = 0; mt < 4; ++mt)
            af[mt] = *(const bf16x8*)&As[(wm * 64 + mt * 16 + l15) * 32 + quad * 8];
#pragma unroll
        for (int nt = 0; nt < 4; ++nt)
            bf[nt] = *(const bf16x8*)&Bs[(wn * 64 + nt * 16 + l15) * 32 + quad * 8];
#pragma unroll
        for (int mt = 0; mt < 4; ++mt)
#pragma unroll
            for (int nt = 0; nt < 4; ++nt)
                acc[mt][nt] = __builtin_amdgcn_mfma_f32_16x16x32_bf16(
                    af[mt], bf[nt], acc[mt][nt], 0, 0, 0);
    }
    __syncthreads();

    float sp[4][4];
#pragma unroll
    for (int mt = 0; mt < 4; ++mt)
#pragma unroll
        for (int rg = 0; rg < 4; ++rg) sp[mt][rg] = 0.f;
#pragma unroll
    for (int nt = 0; nt < 4; ++nt) {
        const int col = nb * 256 + wn * 64 + nt * 16 + l15;
        const float cb = b1[col];
        const float cw = w2[col];
#pragma unroll
        for (int mt = 0; mt < 4; ++mt) {
#pragma unroll
            for (int rg = 0; rg < 4; ++rg)
                sp[mt][rg] += fmaxf(acc[mt][nt][rg] + cb, 0.f) * cw;
        }
    }
#pragma unroll
    for (int mt = 0; mt < 4; ++mt)
#pragma unroll
        for (int rg = 0; rg < 4; ++rg) {
            float v = sp[mt][rg];
            v += __shfl_xor(v, 1);
            v += __shfl_xor(v, 2);
            v += __shfl_xor(v, 4);
            v += __shfl_xor(v, 8);
            if (l15 == 0)
                scred[(wm * 64 + mt * 16 + quad * 4 + rg) * 4 + wn] = v;
        }
    __syncthreads();
    if (tid < 128) {
        float t = scred[tid * 4] + scred[tid * 4 + 1]
                + scred[tid * 4 + 2] + scred[tid * 4 + 3];
        scores4[(long)nb * 131072 + mb * 128 + tid] = t;
    }
}

// ---------------------------------------------------------------- softmax + weighted sum
__global__ __launch_bounds__(256) void softrel_kernel(
    const float* __restrict__ sc4,     // (2, 131072)
    const ushort_t* __restrict__ semb, // (32, 64, 512) bf16
    ushort_t* __restrict__ rel)        // (2048, 512) bf16, rows r = t*B+b
{
    __shared__ float a_s[64];
    const int tid = threadIdx.x;
    const int r = blockIdx.x;
    const int b = r & (WS_B - 1);
    if (tid < 64) {
        float t = sc4[r * 64 + tid] + sc4[131072 + r * 64 + tid];
        float m = t;
#pragma unroll
        for (int off = 32; off > 0; off >>= 1) m = fmaxf(m, __shfl_xor(m, off));
        float e = __expf(t - m);
        float su = e;
#pragma unroll
        for (int off = 32; off > 0; off >>= 1) su += __shfl_xor(su, off);
        a_s[tid] = e / su;
    }
    __syncthreads();
#pragma unroll
    for (int dd = 0; dd < 2; ++dd) {
        const int d = tid + dd * 256;
        float accd = 0.f;
        const ushort_t* sp = semb + (long)b * 64 * 512 + d;
        for (int s = 0; s < 64; ++s)
            accd += a_s[s] * bf2f(sp[s * 512]);
        rel[(long)r * 512 + d] = f2bf(accd);
    }
}

// ---------------------------------------------------------------- attention v2
__global__ __launch_bounds__(256) void attn2_kernel(
    const ushort_t* __restrict__ Qm, int ldq, int qoff,
    const ushort_t* __restrict__ Km, int ldk, int koff,
    const ushort_t* __restrict__ Vm, int ldv, int voff,
    ushort_t* __restrict__ O,          // (2048,512) bf16
    int Lk)
{
    __shared__ float sQT[64 * 34];
    __shared__ float sKT[64 * 68];
    __shared__ float sS[32 * 260];
    __shared__ float sredm[8 * 34];
    __shared__ float sreds[8 * 34];
    const int tid = threadIdx.x;
    const int b  = blockIdx.x >> 4;
    const int h  = (blockIdx.x >> 1) & 7;
    const int qt = blockIdx.x & 1;
    const int L8 = Lk >> 3;

    {
        const int q = tid >> 3, c = tid & 7;
        const int qg = qt * 32 + q;
        const ushort_t* pp = Qm + (long)(qg * WS_B + b) * ldq + qoff + h * 64 + c * 8;
        uint4 u = *(const uint4*)pp;
        const ushort_t* us = (const ushort_t*)&u;
#pragma unroll
        for (int i = 0; i < 8; ++i)
            sQT[(c * 8 + i) * 34 + q] = bf2f(us[i]);
    }

    const int k4 = (tid & 15) * 4;
    const int q2 = (tid >> 4) * 2;

    for (int kt = 0; kt < Lk; kt += 64) {
        __syncthreads();
        {
            const int kk = tid >> 3, c = tid & 7;
#pragma unroll
            for (int half = 0; half < 2; ++half) {
                const int kr = kk + half * 32;
                const ushort_t* pp = Km + (long)((kt + kr) * WS_B + b) * ldk + koff + h * 64 + c * 8;
                uint4 u = *(const uint4*)pp;
                const ushort_t* us = (const ushort_t*)&u;
#pragma unroll
                for (int i = 0; i < 8; ++i)
                    sKT[(c * 8 + i) * 68 + kr] = bf2f(us[i]);
            }
        }
        __syncthreads();
        float acc[2][4] = {{0.f, 0.f, 0.f, 0.f}, {0.f, 0.f, 0.f, 0.f}};
        for (int d = 0; d < 64; ++d) {
            const float qa = sQT[d * 34 + q2];
            const float qb = sQT[d * 34 + q2 + 1];
            const float4 kv = *(const float4*)&sKT[d * 68 + k4];
            acc[0][0] += qa * kv.x; acc[0][1] += qa * kv.y;
            acc[0][2] += qa * kv.z; acc[0][3] += qa * kv.w;
            acc[1][0] += qb * kv.x; acc[1][1] += qb * kv.y;
            acc[1][2] += qb * kv.z; acc[1][3] += qb * kv.w;
        }
#pragma unroll
        for (int i = 0; i < 2; ++i) {
            float4 v;
            v.x = acc[i][0] * 0.125f; v.y = acc[i][1] * 0.125f;
            v.z = acc[i][2] * 0.125f; v.w = acc[i][3] * 0.125f;
            *(float4*)&sS[(q2 + i) * 260 + kt + k4] = v;
        }
    }
    __syncthreads();

    {
        const int q = tid & 31, part = tid >> 5;
        const int kb = part * L8;
        float m = -1e30f;
        for (int k = 0; k < L8; ++k) m = fmaxf(m, sS[q * 260 + kb + k]);
        sredm[part * 34 + q] = m;
        __syncthreads();
        float M = sredm[q];
#pragma unroll
        for (int pz = 1; pz < 8; ++pz) M = fmaxf(M, sredm[pz * 34 + q]);
        float su = 0.f;
        for (int k = 0; k < L8; ++k) {
            float e = __expf(sS[q * 260 + kb + k] - M);
            sS[q * 260 + kb + k] = e;
            su += e;
        }
        sreds[part * 34 + q] = su;
    }
    __syncthreads();

    const int d4 = (tid & 15) * 4;
    float o[2][4] = {{0.f, 0.f, 0.f, 0.f}, {0.f, 0.f, 0.f, 0.f}};
    float* sV = sKT;
    for (int kt = 0; kt < Lk; kt += 64) {
        __syncthreads();
        {
            const int kk = tid >> 3, c = tid & 7;
#pragma unroll
            for (int half = 0; half < 2; ++half) {
                const int kr = kk + half * 32;
                const ushort_t* pp = Vm + (long)((kt + kr) * WS_B + b) * ldv + voff + h * 64 + c * 8;
                uint4 u = *(const uint4*)pp;
                const ushort_t* us = (const ushort_t*)&u;
                float4 w0, w1;
                w0.x = bf2f(us[0]); w0.y = bf2f(us[1]);
                w0.z = bf2f(us[2]); w0.w = bf2f(us[3]);
                w1.x = bf2f(us[4]); w1.y = bf2f(us[5]);
                w1.z = bf2f(us[6]); w1.w = bf2f(us[7]);
                *(float4*)&sV[kr * 68 + c * 8] = w0;
                *(float4*)&sV[kr * 68 + c * 8 + 4] = w1;
            }
        }
        __syncthreads();
        for (int k = 0; k < 64; ++k) {
            const float p0 = sS[q2 * 260 + kt + k];
            const float p1 = sS[(q2 + 1) * 260 + kt + k];
            const float4 vv = *(const float4*)&sV[k * 68 + d4];
            o[0][0] += p0 * vv.x; o[0][1] += p0 * vv.y;
            o[0][2] += p0 * vv.z; o[0][3] += p0 * vv.w;
            o[1][0] += p1 * vv.x; o[1][1] += p1 * vv.y;
            o[1][2] += p1 * vv.z; o[1][3] += p1 * vv.w;
        }
    }

#pragma unroll
    for (int i = 0; i < 2; ++i) {
        float su = 0.f;
#pragma unroll
        for (int pz = 0; pz < 8; ++pz) su += sreds[pz * 34 + q2 + i];
        const float inv = 1.f / su;
        const int qg = qt * 32 + q2 + i;
        ushort_t* op = O + (long)(qg * WS_B + b) * 512 + h * 64 + d4;
        uint2 pk;
        pk.x = packpair(o[i][0] * inv, o[i][1] * inv);
        pk.y = packpair(o[i][2] * inv, o[i][3] * inv);
        *(uint2*)op = pk;
    }
}

// ---------------------------------------------------------------- layernorm (dual out)
__global__ __launch_bounds__(256) void ln_kernel(
    const float* __restrict__ X,
    const float* __restrict__ g,
    const float* __restrict__ be,
    float* __restrict__ Y,
    ushort_t* __restrict__ Yb)
{
    const int row = blockIdx.x * 4 + (threadIdx.x >> 6);
    const int lane = threadIdx.x & 63;
    const float4* xp = (const float4*)(X + (long)row * 512);
    float4 x0 = xp[lane], x1 = xp[lane + 64];
    float sum = x0.x + x0.y + x0.z + x0.w + x1.x + x1.y + x1.z + x1.w;
    float sq = x0.x * x0.x + x0.y * x0.y + x0.z * x0.z + x0.w * x0.w
             + x1.x * x1.x + x1.y * x1.y + x1.z * x1.z + x1.w * x1.w;
#pragma unroll
    for (int off = 32; off > 0; off >>= 1) {
        sum += __shfl_xor(sum, off);
        sq += __shfl_xor(sq, off);
    }
    const float mu = sum * (1.f / 512.f);
    const float var = sq * (1.f / 512.f) - mu * mu;
    const float rs = rsqrtf(var + 1e-5f);
    const float4* gp = (const float4*)g;
    const float4* bp = (const float4*)be;
    float4 g0 = gp[lane], g1 = gp[lane + 64], b0 = bp[lane], b1 = bp[lane + 64];
    float4 y0, y1;
    y0.x = (x0.x - mu) * rs * g0.x + b0.x;
    y0.y = (x0.y - mu) * rs * g0.y + b0.y;
    y0.z = (x0.z - mu) * rs * g0.z + b0.z;
    y0.w = (x0.w - mu) * rs * g0.w + b0.w;
    y1.x = (x1.x - mu) * rs * g1.x + b1.x;
    y1.y = (x1.y - mu) * rs * g1.y + b1.y;
    y1.z = (x1.z - mu) * rs * g1.z + b1.z;
    y1.w = (x1.w - mu) * rs * g1.w + b1.w;
    float4* yp = (float4*)(Y + (long)row * 512);
    yp[lane] = y0; yp[lane + 64] = y1;
    if (Yb) {
        uint2* ybp = (uint2*)(Yb + (long)row * 512);
        uint2 p0, p1;
        p0.x = packpair(y0.x, y0.y); p0.y = packpair(y0.z, y0.w);
        p1.x = packpair(y1.x, y1.y); p1.y = packpair(y1.z, y1.w);
        ybp[lane] = p0; ybp[lane + 64] = p1;
    }
}

// ---------------------------------------------------------------- launch helpers
static inline GemmDesc mkdesc(const ushort_t* A, int lda, const ushort_t* W, int ldw,
                              const float* bias, const float* resid, float* C,
                              ushort_t* Cb, int ldc, int N, int K, int relu,
                              int blkStart)
{
    GemmDesc d;
    d.A = A; d.W = W; d.bias = bias; d.resid = resid; d.C = C; d.Cb = Cb;
    d.lda = lda; d.ldw = ldw; d.ldc = ldc; d.K = K; d.relu = relu;
    d.nbx = N / 128;
    d.blkStart = blkStart;
    return d;
}
// 64x128 tile variant for M=2048 chain GEMMs
static inline void mgemm3(hipStream_t s, const ushort_t* A, int lda,
                          const ushort_t* W, int ldw, const float* bias,
                          const float* resid, float* C, ushort_t* Cb,
                          int ldc, int M, int N, int K, bool relu)
{
    GemmBatch bt;
    bt.nd = 1;
    bt.d[0] = mkdesc(A, lda, W, ldw, bias, resid, C, Cb, ldc, N, K, relu ? 1 : 0, 0);
    bt.d[1] = bt.d[0]; bt.d[2] = bt.d[0]; bt.d[3] = bt.d[0];
    mfma_gemm3<<<(M / 64) * (N / 128), 128, 0, s>>>(bt);
}

extern "C" void kernel_launch(void* const* d_in, const int* in_sizes, int n_in,
                              void* d_out, int out_size, void* d_ws, size_t ws_size,
                              hipStream_t stream)
{
    (void)in_sizes; (void)n_in; (void)out_size; (void)ws_size;
    const float* tgt       = (const float*)d_in[0];
    const float* memory    = (const float*)d_in[1];
    const float* semantics = (const float*)d_in[2];
    const float* pt_wqkv   = (const float*)d_in[3];
    const float* pt_bqkv   = (const float*)d_in[4];
    const float* pt_wo     = (const float*)d_in[5];
    const float* pt_bo     = (const float*)d_in[6];
    const float* sa_wqkv   = (const float*)d_in[7];
    const float* sa_bqkv   = (const float*)d_in[8];
    const float* sa_wo     = (const float*)d_in[9];
    const float* sa_bo     = (const float*)d_in[10];
    const float* ca_wqkv   = (const float*)d_in[11];
    const float* ca_bqkv   = (const float*)d_in[12];
    const float* ca_wo     = (const float*)d_in[13];
    const float* ca_bo     = (const float*)d_in[14];
    const float* mlp_w0    = (const float*)d_in[15];
    const float* mlp_b0    = (const float*)d_in[16];
    const float* mlp_w1    = (const float*)d_in[17];
    const float* mlp_b1    = (const float*)d_in[18];
    const float* mlp_w2    = (const float*)d_in[19];
    const float* ffn_w1    = (const float*)d_in[21];
    const float* ffn_b1    = (const float*)d_in[22];
    const float* ffn_w2    = (const float*)d_in[23];
    const float* ffn_b2    = (const float*)d_in[24];
    const float* ln1_g     = (const float*)d_in[25];
    const float* ln1_b     = (const float*)d_in[26];
    const float* ln2_g     = (const float*)d_in[27];
    const float* ln2_b     = (const float*)d_in[28];
    const float* ln3_g     = (const float*)d_in[29];
    const float* ln3_b     = (const float*)d_in[30];

    char* p = (char*)d_ws;
    // weights (persist): [0, 11.5 MB)
    ushort_t* w0b   = (ushort_t*)(p + 0);          // 512x1024   1.0 MB
    ushort_t* w1b   = (ushort_t*)(p + MB(1));      // 512x512    0.5
    ushort_t* ptwb  = (ushort_t*)(p + 1572864);    // 1536x512   1.5
    ushort_t* ptob  = (ushort_t*)(p + MB(3));      // 512x512    0.5
    ushort_t* sawb  = (ushort_t*)(p + 3670016);    // 1536x512   1.5
    ushort_t* saob  = (ushort_t*)(p + MB(5));      // 512x512    0.5
    ushort_t* cawb  = (ushort_t*)(p + 5767168);    // 1536x512   1.5
    ushort_t* caob  = (ushort_t*)(p + MB(7));      // 512x512    0.5
    ushort_t* f1b   = (ushort_t*)(p + 7864320);    // 2048x512   2.0
    ushort_t* f2b   = (ushort_t*)(p + 9961472);    // 512x2048   2.0
    // activations:
    ushort_t* memb  = (ushort_t*)(p + MB(12));     // 8192x512   8   (dies @cakv)
    ushort_t* cakvb = (ushort_t*)(p + MB(20));     // 8192x1024 16   (-> attn ca)
    ushort_t* tgtb  = (ushort_t*)(p + MB(36));     // 2048x512   2
    ushort_t* semb  = (ushort_t*)(p + MB(38));     // 2048x512   2
    ushort_t* Fb    = (ushort_t*)(p + MB(40));     // 2
    ushort_t* Sb    = (ushort_t*)(p + MB(42));     // 2
    float*    scores4 = (float*)(p + MB(44));      // 1
    ushort_t* relb  = (ushort_t*)(p + MB(45));     // 2
    ushort_t* Ob    = (ushort_t*)(p + MB(47));     // 2
    float*    x1f   = (float*)(p + MB(49));        // 4
    ushort_t* ptqb  = (ushort_t*)(p + MB(53));     // 2  [53,55) — NOT over memb
    // aliases over dead regions:
    ushort_t* ptkvb = (ushort_t*)(p + MB(14));     // 4  over memb (dead after cakv)
    ushort_t* x1b   = (ushort_t*)(p + MB(18));     // 2  over memb
    ushort_t* saqkvb= (ushort_t*)(p + MB(38));     // 6  over semb/Fb/Sb (dead)
    float*    yf    = (float*)(p + MB(12));        // 4  over memb head (dead)
    float*    x2f   = (float*)(p + MB(16));        // 4  over ptkvb (dead by then)
    ushort_t* x2b   = (ushort_t*)(p + MB(36));     // 2  over tgtb (dead)
    ushort_t* caqb  = (ushort_t*)(p + MB(44));     // 2  over scores4/relb (dead)
    float*    x3f   = (float*)(p + MB(40));        // 4  over saqkvb (dead)
    ushort_t* x3b   = (ushort_t*)(p + MB(38));     // 2  over saqkvb (dead)
    ushort_t* hb    = (ushort_t*)(p + MB(20));     // 8  over cakvb (dead)

    // ---- 1. convert everything to bf16 (one launch)
    CvtArgs ca;
    ca.src[0]  = tgt;       ca.dst[0]  = tgtb;  ca.n4[0]  = 262144;
    ca.src[1]  = semantics; ca.dst[1]  = semb;  ca.n4[1]  = 262144;
    ca.src[2]  = memory;    ca.dst[2]  = memb;  ca.n4[2]  = 1048576;
    ca.src[3]  = mlp_w0;    ca.dst[3]  = w0b;   ca.n4[3]  = 131072;
    ca.src[4]  = mlp_w1;    ca.dst[4]  = w1b;   ca.n4[4]  = 65536;
    ca.src[5]  = pt_wqkv;   ca.dst[5]  = ptwb;  ca.n4[5]  = 196608;
    ca.src[6]  = pt_wo;     ca.dst[6]  = ptob;  ca.n4[6]  = 65536;
    ca.src[7]  = sa_wqkv;   ca.dst[7]  = sawb;  ca.n4[7]  = 196608;
    ca.src[8]  = sa_wo;     ca.dst[8]  = saob;  ca.n4[8]  = 65536;
    ca.src[9]  = ca_wqkv;   ca.dst[9]  = cawb;  ca.n4[9]  = 196608;
    ca.src[10] = ca_wo;     ca.dst[10] = caob;  ca.n4[10] = 65536;
    ca.src[11] = ffn_w1;    ca.dst[11] = f1b;   ca.n4[11] = 262144;
    ca.src[12] = ffn_w2;    ca.dst[12] = f2b;   ca.n4[12] = 262144;
    megacvt_kernel<<<dim3(1024, 13), 256, 0, stream>>>(ca);

    // ---- 2. batched independent GEMMs: cakv(512) + F(64) + Smat(64) + ptq(64)
    {
        GemmBatch bt;
        bt.nd = 4;
        bt.d[0] = mkdesc(memb, 512, cawb + 512 * 512, 512, ca_bqkv + 512, nullptr,
                         nullptr, cakvb, 1024, 1024, 512, 0, 0);
        bt.d[1] = mkdesc(tgtb, 512, w0b, 1024, mlp_b0, nullptr,
                         nullptr, Fb, 512, 512, 512, 0, 512);
        bt.d[2] = mkdesc(semb, 512, w0b + 512, 1024, nullptr, nullptr,
                         nullptr, Sb, 512, 512, 512, 0, 576);
        bt.d[3] = mkdesc(tgtb, 512, ptwb, 512, pt_bqkv, nullptr,
                         nullptr, ptqb, 512, 512, 512, 0, 640);
        mfma_gemm2<<<704, 256, 0, stream>>>(bt);
    }

    // ---- rel path
    h2score_kernel<<<dim3(1024, 2), 512, 0, stream>>>(Fb, Sb, w1b, mlp_b1,
                                                      mlp_w2, scores4);
    softrel_kernel<<<2048, 256, 0, stream>>>(scores4, semb, relb);

    // ---- pt attention
    mgemm3(stream, relb, 512, ptwb + 512 * 512, 512, pt_bqkv + 512, nullptr,
           nullptr, ptkvb, 1024, 2048, 1024, 512, false);
    attn2_kernel<<<512, 256, 0, stream>>>(ptqb, 512, 0, ptkvb, 1024, 0,
                                          ptkvb, 1024, 512, Ob, 64);
    mgemm3(stream, Ob, 512, ptob, 512, pt_bo, tgt, x1f, x1b, 512,
           2048, 512, 512, false);

    // ---- self attention + ln1
    mgemm3(stream, x1b, 512, sawb, 512, sa_bqkv, nullptr, nullptr, saqkvb, 1536,
           2048, 1536, 512, false);
    attn2_kernel<<<512, 256, 0, stream>>>(saqkvb, 1536, 0, saqkvb, 1536, 512,
                                          saqkvb, 1536, 1024, Ob, 64);
    mgemm3(stream, Ob, 512, saob, 512, sa_bo, x1f, yf, nullptr, 512,
           2048, 512, 512, false);
    ln_kernel<<<512, 256, 0, stream>>>(yf, ln1_g, ln1_b, x2f, x2b);

    // ---- cross attention + ln2
    mgemm3(stream, x2b, 512, cawb, 512, ca_bqkv, nullptr, nullptr, caqb, 512,
           2048, 512, 512, false);
    attn2_kernel<<<512, 256, 0, stream>>>(caqb, 512, 0, cakvb, 1024, 0,
                                          cakvb, 1024, 512, Ob, 256);
    mgemm3(stream, Ob, 512, caob, 512, ca_bo, x2f, yf, nullptr, 512,
           2048, 512, 512, false);
    ln_kernel<<<512, 256, 0, stream>>>(yf, ln2_g, ln2_b, x3f, x3b);

    // ---- FFN + ln3 -> out
    mgemm3(stream, x3b, 512, f1b, 512, ffn_b1, nullptr, nullptr, hb, 2048,
           2048, 2048, 512, true);
    mgemm3(stream, hb, 2048, f2b, 2048, ffn_b2, x3f, yf, nullptr, 512,
           2048, 512, 2048, false);
    ln_kernel<<<512, 256, 0, stream>>>(yf, ln3_g, ln3_b, (float*)d_out, nullptr);
}